// Round 2
// baseline (110.038 us; speedup 1.0000x reference)
//
#include <hip/hip_runtime.h>

#define Bv 4
#define Vv 50000
#define Cv 160

// Kernel 1: per-(b,c) affine table A[b][c][12]:
//   A[0..8]  = R row-major (rows b1,b2,b3)
//   A[9..11] = center + V_nodes - R*center
// so out[b,v,:] = M·x_v + t with [M|t] = sum_c W[v,c]*A[b,c,:]
__global__ void precompute_A(const float* __restrict__ X,
                             const float* __restrict__ Vn,
                             const float* __restrict__ r6,
                             const int* __restrict__ idx,
                             float* __restrict__ A) {
    int i = blockIdx.x * blockDim.x + threadIdx.x;
    if (i >= Bv * Cv) return;
    int b = i / Cv, c = i % Cv;

    const float* d6 = r6 + (size_t)(b * Cv + c) * 6;
    float a1x = d6[0], a1y = d6[1], a1z = d6[2];
    float a2x = d6[3], a2y = d6[4], a2z = d6[5];

    float n1 = fmaxf(sqrtf(a1x*a1x + a1y*a1y + a1z*a1z), 1e-8f);
    float b1x = a1x / n1, b1y = a1y / n1, b1z = a1z / n1;

    float d = b1x*a2x + b1y*a2y + b1z*a2z;
    float px = a2x - d*b1x, py = a2y - d*b1y, pz = a2z - d*b1z;
    float n2 = fmaxf(sqrtf(px*px + py*py + pz*pz), 1e-8f);
    float b2x = px / n2, b2y = py / n2, b2z = pz / n2;

    float b3x = b1y*b2z - b1z*b2y;
    float b3y = b1z*b2x - b1x*b2z;
    float b3z = b1x*b2y - b1y*b2x;

    int iv = idx[c];
    const float* xc = X + ((size_t)b * Vv + iv) * 3;
    float cx = xc[0], cy = xc[1], cz = xc[2];
    const float* vn = Vn + (size_t)(b * Cv + c) * 3;
    float vx = vn[0], vy = vn[1], vz = vn[2];

    float* Ao = A + (size_t)(b * Cv + c) * 12;
    Ao[0] = b1x; Ao[1] = b1y; Ao[2] = b1z;
    Ao[3] = b2x; Ao[4] = b2y; Ao[5] = b2z;
    Ao[6] = b3x; Ao[7] = b3y; Ao[8] = b3z;
    Ao[9]  = cx + vx - (b1x*cx + b1y*cy + b1z*cz);
    Ao[10] = cy + vy - (b2x*cx + b2y*cy + b2z*cz);
    Ao[11] = cz + vz - (b3x*cx + b3y*cy + b3z*cz);
}

// Kernel 2: block = 64 vertices x 4 waves; wave w handles batch b=w.
// W rows staged once per block into LDS (reused by all 4 batches).
#define WSTRIDE 161  // odd stride: bank = (lane + c) % 32 -> 2 lanes/bank (free)
__global__ __launch_bounds__(256) void deform_main(const float* __restrict__ X,
                                                   const float* __restrict__ W,
                                                   const float* __restrict__ A,
                                                   float* __restrict__ out) {
    __shared__ float Wl[64 * WSTRIDE];  // 41.2 KB

    const int tid = threadIdx.x;
    const int v0 = blockIdx.x * 64;
    const int nrows = min(64, Vv - v0);

    // Stage W rows [v0, v0+nrows): coalesced float4 reads (rows are 640 B,
    // 16B-aligned).
    for (int i4 = tid; i4 < nrows * 40; i4 += 256) {
        int v  = i4 / 40;
        int c4 = i4 % 40;
        float4 q = ((const float4*)(W + (size_t)(v0 + v) * Cv))[c4];
        float* dst = &Wl[v * WSTRIDE + c4 * 4];
        dst[0] = q.x; dst[1] = q.y; dst[2] = q.z; dst[3] = q.w;
    }
    __syncthreads();

    const int lane = tid & 63;
    const int b = __builtin_amdgcn_readfirstlane(tid >> 6);  // wave-uniform batch
    const int v = v0 + lane;
    const bool valid = (v < Vv);
    const int vc = valid ? v : (Vv - 1);

    const float* xp = X + ((size_t)b * Vv + vc) * 3;
    float x0 = xp[0], x1 = xp[1], x2 = xp[2];

    const float* __restrict__ Ab = A + (size_t)b * Cv * 12;  // wave-uniform -> s_load
    const float* wrow = &Wl[lane * WSTRIDE];

    float acc[12];
#pragma unroll
    for (int j = 0; j < 12; ++j) acc[j] = 0.0f;

#pragma unroll 4
    for (int c = 0; c < Cv; ++c) {
        float w = wrow[c];
        const float* a = Ab + c * 12;
#pragma unroll
        for (int j = 0; j < 12; ++j) acc[j] = fmaf(w, a[j], acc[j]);
    }

    if (valid) {
        float o0 = acc[0]*x0 + acc[1]*x1 + acc[2]*x2 + acc[9];
        float o1 = acc[3]*x0 + acc[4]*x1 + acc[5]*x2 + acc[10];
        float o2 = acc[6]*x0 + acc[7]*x1 + acc[8]*x2 + acc[11];
        float* op = out + ((size_t)b * Vv + v) * 3;
        op[0] = o0; op[1] = o1; op[2] = o2;
    }
}

extern "C" void kernel_launch(void* const* d_in, const int* in_sizes, int n_in,
                              void* d_out, int out_size, void* d_ws, size_t ws_size,
                              hipStream_t stream) {
    const float* X   = (const float*)d_in[0];  // (B,V,3) fp32
    const float* Vn  = (const float*)d_in[1];  // (B,C,3) fp32
    const float* r6  = (const float*)d_in[2];  // (B,C,6) fp32
    const float* W   = (const float*)d_in[3];  // (V,C)   fp32
    const int*   idx = (const int*)d_in[4];    // (C,)    int32
    float* out = (float*)d_out;                // (B,V,3) fp32
    float* A = (float*)d_ws;                   // B*C*12 floats = 30720 B

    precompute_A<<<(Bv * Cv + 255) / 256, 256, 0, stream>>>(X, Vn, r6, idx, A);
    deform_main<<<(Vv + 63) / 64, 256, 0, stream>>>(X, W, A, out);
}